// Round 3
// baseline (186.222 us; speedup 1.0000x reference)
//
#include <hip/hip_runtime.h>
#include <hip/hip_bf16.h>
#include <math.h>

#define L_SEQ 1024
#define BSZ 8
#define EMB 512
#define NH 8
#define DQ 64
#define BH 64          // BSZ*NH
#define NQKV 1536      // 3*NH*DQ

// Q is pre-scaled by (emb_dim/n_head)^-0.5 * log2(e) so that
// softmax numerator = exp2(mfma_score) with zero extra VALU per element.
#define SCALE_Q 0.18033688f

typedef __attribute__((ext_vector_type(8))) short short8;   // 8 bf16 = 4 VGPR
typedef __attribute__((ext_vector_type(4))) float f32x4;

#define GPTR(x) ((const __attribute__((address_space(1))) void*)(x))
#define LPTR(x) ((__attribute__((address_space(3))) void*)(x))

__device__ __forceinline__ unsigned short bf16u(float x) {
  __hip_bfloat16 h = __float2bfloat16(x);
  return *(unsigned short*)&h;
}

// ---------------------------------------------------------------------------
// Kernel 0: f32 -> bf16 convert of emb (8192x512) and W (1536x512).
// v8: block 0 additionally zero-inits Oacc[64*64] and cnt[64] (the fused
// attention kernel can no longer do it itself -- it needs cnt zeroed
// before ANY of its blocks run; stream order guarantees this here).
// ---------------------------------------------------------------------------
__global__ __launch_bounds__(256) void to_bf16(
    const float* __restrict__ emb, const float* __restrict__ W,
    unsigned short* __restrict__ embB, unsigned short* __restrict__ WB,
    float* __restrict__ Oacc, int* __restrict__ cnt) {
  const int tid = threadIdx.x;
  if (blockIdx.x == 0) {
    for (int i = tid; i < BH * DQ; i += 256) Oacc[i] = 0.f;
    if (tid < BH) cnt[tid] = 0;
  }
  const size_t t = (size_t)blockIdx.x * 256 + tid;
  size_t base = t * 8;
  const float* src;
  unsigned short* dst;
  size_t off;
  if (base < (size_t)8192 * 512) { src = emb; dst = embB; off = base; }
  else { src = W; dst = WB; off = base - (size_t)8192 * 512; }
  float4 v0 = *(const float4*)&src[off];
  float4 v1 = *(const float4*)&src[off + 4];
  short8 o;
  o[0] = bf16u(v0.x); o[1] = bf16u(v0.y); o[2] = bf16u(v0.z); o[3] = bf16u(v0.w);
  o[4] = bf16u(v1.x); o[5] = bf16u(v1.y); o[6] = bf16u(v1.z); o[7] = bf16u(v1.w);
  *(short8*)&dst[off] = o;
}

// ---------------------------------------------------------------------------
// Kernel A: QKV projection, bf16 MFMA (m97 pattern). Q gets SCALE_Q folded in.
// v8: two-pass C epilogue through Cs[128][68] (17 KB instead of 33 KB).
// LDS total 33 KB -> 4 blocks/CU by LDS; __launch_bounds__(256,4) caps
// VGPR at 128 so occupancy actually reaches 4 blocks/CU (16 waves/CU).
// Rationale: the m97 structure's ~20% stall is the vmcnt(0) drain before
// each barrier; more resident blocks hide it (implicit overlap, m114).
// XCD swizzle (v7) kept: sid = (id&7)*96 + (id>>3).
// ---------------------------------------------------------------------------
__global__ __launch_bounds__(256, 4) void qkv_mfma(
    const unsigned short* __restrict__ A,   // embB [8192][512]
    const unsigned short* __restrict__ B,   // WB   [1536][512]
    const float* __restrict__ bias,
    unsigned short* __restrict__ Qb, unsigned short* __restrict__ Kb,
    unsigned short* __restrict__ Vb) {
  __shared__ __align__(16) unsigned short As[128][32];  // 8 KB, unpadded
  __shared__ __align__(16) unsigned short Bs[128][32];  // 8 KB
  __shared__ __align__(16) unsigned short Cs[128][68];  // 17 KB, +4 pad
  const int tid = threadIdx.x;
  const int wave = tid >> 6, lane = tid & 63;
  const int quad = lane >> 4, col = lane & 15;
  const int wr = wave >> 1, wc = wave & 1;
  // XCD swizzle: 768 blocks, xcd = id&7 (round-robin dispatch), 96 tiles/XCD
  const int id = blockIdx.x;
  const int sid = (id & 7) * 96 + (id >> 3);
  const int mb = sid / 12, nb = sid - mb * 12;
  const int m0 = mb * 128, n0 = nb * 128;
  const int r16 = lane >> 2, q4 = lane & 3;

  f32x4 acc[4][4] = {};

  for (int kt = 0; kt < EMB; kt += 32) {
    __syncthreads();
#pragma unroll
    for (int c = 0; c < 2; ++c) {
      const int rowA = (c * 4 + wave) * 16;
      __builtin_amdgcn_global_load_lds(
          GPTR(A + (size_t)(m0 + rowA + r16) * EMB + kt + q4 * 8),
          LPTR(&As[rowA][0]), 16, 0, 0);
      __builtin_amdgcn_global_load_lds(
          GPTR(B + (size_t)(n0 + rowA + r16) * EMB + kt + q4 * 8),
          LPTR(&Bs[rowA][0]), 16, 0, 0);
    }
    __syncthreads();
    short8 af[4], bf[4];
#pragma unroll
    for (int i = 0; i < 4; ++i)
      af[i] = *(const short8*)&As[wr * 64 + i * 16 + col][quad * 8];
#pragma unroll
    for (int j = 0; j < 4; ++j)
      bf[j] = *(const short8*)&Bs[wc * 64 + j * 16 + col][quad * 8];
#pragma unroll
    for (int i = 0; i < 4; ++i)
#pragma unroll
      for (int j = 0; j < 4; ++j)
        acc[i][j] =
            __builtin_amdgcn_mfma_f32_16x16x32_bf16(af[i], bf[j], acc[i][j],
                                                    0, 0, 0);
  }

  // Two-pass epilogue: half h covers C cols [h*64, h*64+64). The waves with
  // wc==h own those accumulators; all waves then store the staged half.
  const int bb = lane >> 3, oct = lane & 7;
#pragma unroll
  for (int h = 0; h < 2; ++h) {
    __syncthreads();   // h=0: main-loop LDS reads done; h=1: h=0 reads done
    if (wc == h) {
#pragma unroll
      for (int j = 0; j < 4; ++j) {
        const int n = j * 16 + col;               // col within half
        const float bj = bias[n0 + h * 64 + n];
        const bool isQ = (((n0 + h * 64 + n) >> 6) % 3) == 0;
#pragma unroll
        for (int i = 0; i < 4; ++i) {
          const int mrow = wr * 64 + i * 16 + quad * 4;
#pragma unroll
          for (int r = 0; r < 4; ++r) {
            float val = acc[i][j][r] + bj;
            if (isQ) val *= SCALE_Q;
            Cs[mrow + r][n] = bf16u(val);
          }
        }
      }
    }
    __syncthreads();
    const int G = (n0 >> 6) + h;          // 64-col block id, 0..23
    const int hd = G / 3, sel = G % 3;
    unsigned short* dst = (sel == 0) ? Qb : (sel == 1) ? Kb : Vb;
#pragma unroll
    for (int e = 0; e < 4; ++e) {
      const int l = wave * 4 + e;         // 0..15
      short8 v = *(const short8*)&Cs[l * 8 + bb][oct * 8];
      const int lglob = (m0 >> 3) + l;
      *(short8*)&dst[(((size_t)(bb * NH + hd)) * L_SEQ + lglob) * DQ + oct * 8] = v;
    }
  }
}

// ---------------------------------------------------------------------------
// Kernel B (fused): z-pass + aw-pass in ONE kernel, per-bh spin sync.
// Grid 512 = (bh = blk&63, qc = blk>>6). Phase Z: this block's 128 q-rows
// vs all K (8 dbuf tiles of 128) -> invz. Then per-bh barrier: atomicAdd
// cnt[bh] (release fence), spin until all 8 sibling blocks signed in
// (acquire). All 8 siblings share an XCD (blk%8 == bh%8) and the whole
// grid is co-resident (512 blocks <= 3-blocks/CU capacity of 768), so the
// spin cannot deadlock. Phase AW: this block's 128 keys (kc=qc) vs all Q
// (8 dbuf tiles reusing the SAME LDS buffer) -> aw -> local V-combine ->
// atomicAdd Oacc; 16th sign-in does GroupNorm + out.
// Removes one full-grid kernel boundary (drain+launch+refill bubble);
// blocks of different bh flow through the spin independently.
// ---------------------------------------------------------------------------
__global__ __launch_bounds__(256) void attn_fused(
    const unsigned short* __restrict__ Qb, const unsigned short* __restrict__ Kb,
    const unsigned short* __restrict__ Vb, float* __restrict__ invz,
    const float* __restrict__ gnw, const float* __restrict__ gnb,
    float* __restrict__ Oacc, int* __restrict__ cnt, float* __restrict__ out) {
  const int bh = blockIdx.x & 63;   // blk%8 = bh%8 -> same-bh blocks same XCD
  const int qc = blockIdx.x >> 6;   // 0..7: q-chunk in Z, k-chunk in AW
  const int tid = threadIdx.x;
  const int wave = tid >> 6, lane = tid & 63;
  const int quad = lane >> 4, col = lane & 15;

  __shared__ __align__(16) unsigned short Ts[2][128][72];  // 36.9 KB, both phases
  __shared__ float izs[1024];                              // 4 KB
  __shared__ float aws[128];
  __shared__ float red[4][64];
  __shared__ int lastFlag;

  const unsigned short* kbase = &Kb[(size_t)bh * L_SEQ * DQ];
  const unsigned short* qbase = &Qb[(size_t)bh * L_SEQ * DQ];

  const int srow = tid >> 3;        // staging row 0..31 (+32*chunk)
  const int scol = (tid & 7) * 8;   // staging col (shorts)

  // ===================== Phase Z =====================
  short8 qa[2][2];
#pragma unroll
  for (int i = 0; i < 2; ++i) {
    const unsigned short* qp =
        qbase + ((size_t)qc * 128 + wave * 32 + i * 16 + col) * DQ;
    qa[i][0] = *(const short8*)&qp[quad * 8];
    qa[i][1] = *(const short8*)&qp[32 + quad * 8];
  }

  float zacc[2][4] = {};

  short8 st0, st1, st2, st3;
  {  // prefetch K tile 0 (16 KB contiguous)
    st0 = *(const short8*)(kbase + (size_t)tid * 8);
    st1 = *(const short8*)(kbase + 2048 + (size_t)tid * 8);
    st2 = *(const short8*)(kbase + 4096 + (size_t)tid * 8);
    st3 = *(const short8*)(kbase + 6144 + (size_t)tid * 8);
  }

#pragma unroll 2
  for (int kt = 0; kt < 8; ++kt) {
    const int buf = kt & 1;
    *(short8*)&Ts[buf][srow][scol] = st0;
    *(short8*)&Ts[buf][32 + srow][scol] = st1;
    *(short8*)&Ts[buf][64 + srow][scol] = st2;
    *(short8*)&Ts[buf][96 + srow][scol] = st3;
    __syncthreads();
    if (kt + 1 < 8) {  // post-barrier prefetch: in flight through compute
      const unsigned short* nb = kbase + (size_t)(kt + 1) * 8192;
      st0 = *(const short8*)(nb + (size_t)tid * 8);
      st1 = *(const short8*)(nb + 2048 + (size_t)tid * 8);
      st2 = *(const short8*)(nb + 4096 + (size_t)tid * 8);
      st3 = *(const short8*)(nb + 6144 + (size_t)tid * 8);
    }
#pragma unroll
    for (int sub = 0; sub < 8; ++sub) {
      const unsigned short* kp = &Ts[buf][sub * 16 + col][0];
      short8 kb0 = *(const short8*)&kp[quad * 8];
      short8 kb1 = *(const short8*)&kp[32 + quad * 8];
#pragma unroll
      for (int i = 0; i < 2; ++i) {
        f32x4 s = {0.f, 0.f, 0.f, 0.f};
        s = __builtin_amdgcn_mfma_f32_16x16x32_bf16(qa[i][0], kb0, s, 0, 0, 0);
        s = __builtin_amdgcn_mfma_f32_16x16x32_bf16(qa[i][1], kb1, s, 0, 0, 0);
#pragma unroll
        for (int j = 0; j < 4; ++j) zacc[i][j] += __builtin_amdgcn_exp2f(s[j]);
      }
    }
  }
  {
    float* dst = &invz[(size_t)bh * L_SEQ + qc * 128 + wave * 32];
#pragma unroll
    for (int i = 0; i < 2; ++i)
#pragma unroll
      for (int j = 0; j < 4; ++j) {
        float z = zacc[i][j];
#pragma unroll
        for (int off = 1; off <= 8; off <<= 1) z += __shfl_xor(z, off, 64);
        if (col == j)
          dst[i * 16 + quad * 4 + j] = __builtin_amdgcn_rcpf(z);
      }
  }

  // ============= per-bh sign-in + spin =============
  if (tid == 0) {
    __threadfence();                      // release: invz writes visible first
    atomicAdd(&cnt[bh], 1);
    while (__hip_atomic_load(&cnt[bh], __ATOMIC_ACQUIRE,
                             __HIP_MEMORY_SCOPE_AGENT) < 8)
      __builtin_amdgcn_s_sleep(1);
  }
  __syncthreads();
  __threadfence();                        // acquire: fresh invz for all threads

  // ===================== Phase AW =====================
  const int kc = qc;
  short8 kA[2][2];
#pragma unroll
  for (int i = 0; i < 2; ++i) {
    const unsigned short* kp0 =
        kbase + ((size_t)kc * 128 + wave * 32 + i * 16 + col) * DQ;
    kA[i][0] = *(const short8*)&kp0[quad * 8];
    kA[i][1] = *(const short8*)&kp0[32 + quad * 8];
  }

  {  // stage invz for this bh (read-protected by first in-loop barrier)
    const float4 v = *(const float4*)&invz[(size_t)bh * L_SEQ + tid * 4];
    *(float4*)&izs[tid * 4] = v;
  }

  float acc[2][4] = {};

  {  // prefetch Q tile 0
    st0 = *(const short8*)(qbase + (size_t)tid * 8);
    st1 = *(const short8*)(qbase + 2048 + (size_t)tid * 8);
    st2 = *(const short8*)(qbase + 4096 + (size_t)tid * 8);
    st3 = *(const short8*)(qbase + 6144 + (size_t)tid * 8);
  }

#pragma unroll 2
  for (int qt = 0; qt < 8; ++qt) {
    const int buf = qt & 1;
    *(short8*)&Ts[buf][srow][scol] = st0;
    *(short8*)&Ts[buf][32 + srow][scol] = st1;
    *(short8*)&Ts[buf][64 + srow][scol] = st2;
    *(short8*)&Ts[buf][96 + srow][scol] = st3;
    __syncthreads();
    if (qt + 1 < 8) {  // post-barrier prefetch
      const unsigned short* nb = qbase + (size_t)(qt + 1) * 8192;
      st0 = *(const short8*)(nb + (size_t)tid * 8);
      st1 = *(const short8*)(nb + 2048 + (size_t)tid * 8);
      st2 = *(const short8*)(nb + 4096 + (size_t)tid * 8);
      st3 = *(const short8*)(nb + 6144 + (size_t)tid * 8);
    }
#pragma unroll
    for (int sub = 0; sub < 8; ++sub) {
      const unsigned short* qp = &Ts[buf][sub * 16 + col][0];
      short8 qb0 = *(const short8*)&qp[quad * 8];
      short8 qb1 = *(const short8*)&qp[32 + quad * 8];
      const float ivzv = izs[qt * 128 + sub * 16 + col];
#pragma unroll
      for (int i = 0; i < 2; ++i) {
        f32x4 s = {0.f, 0.f, 0.f, 0.f};
        s = __builtin_amdgcn_mfma_f32_16x16x32_bf16(kA[i][0], qb0, s, 0, 0, 0);
        s = __builtin_amdgcn_mfma_f32_16x16x32_bf16(kA[i][1], qb1, s, 0, 0, 0);
#pragma unroll
        for (int r = 0; r < 4; ++r)
          acc[i][r] = fmaf(__builtin_amdgcn_exp2f(s[r]), ivzv, acc[i][r]);
      }
    }
  }
  // butterfly over the 16 query-lanes; lane col==r holds key quad*4+r
#pragma unroll
  for (int i = 0; i < 2; ++i)
#pragma unroll
    for (int r = 0; r < 4; ++r) {
      float a = acc[i][r];
#pragma unroll
      for (int off = 1; off <= 8; off <<= 1) a += __shfl_xor(a, off, 64);
      if (col == r) aws[wave * 32 + i * 16 + quad * 4 + r] = a;
    }
  __syncthreads();

  // local V-combine over this block's 128 keys (4 groups x 32 keys)
  const int d = tid & 63, g4 = tid >> 6;
  float oacc = 0.f;
#pragma unroll 8
  for (int mm = 0; mm < 32; ++mm) {
    const int m = g4 * 32 + mm;
    __hip_bfloat16 v;
    *(unsigned short*)&v =
        Vb[((size_t)bh * L_SEQ + kc * 128 + m) * DQ + d];
    oacc = fmaf(aws[m], __bfloat162float(v), oacc);
  }
  red[g4][d] = oacc;
  __syncthreads();
  if (tid < 64) {
    float p = red[0][tid] + red[1][tid] + red[2][tid] + red[3][tid];
    atomicAdd(&Oacc[(size_t)bh * 64 + tid], p);
  }
  if (tid == 0) {
    __threadfence();                      // release: O adds visible first
    lastFlag = (atomicAdd(&cnt[bh], 1) == 15);  // values 9..16 in this phase
  }
  __syncthreads();
  if (lastFlag && tid < 64) {
    __threadfence();                      // acquire
    float v = atomicAdd(&Oacc[(size_t)bh * 64 + tid], 0.f);
    float s = v;
#pragma unroll
    for (int off = 32; off >= 1; off >>= 1) s += __shfl_xor(s, off, 64);
    float mean = s * (1.f / 64.f);
    float diff = v - mean;
    float sq = diff * diff;
#pragma unroll
    for (int off = 32; off >= 1; off >>= 1) sq += __shfl_xor(sq, off, 64);
    float var = sq * (1.f / 64.f);
    float o = diff * rsqrtf(var + 1e-5f);
    const int b = bh >> 3, h = bh & 7;
    out[(size_t)b * 512 + h * 64 + tid] = o * gnw[h] + gnb[h];
  }
}

extern "C" void kernel_launch(void* const* d_in, const int* in_sizes, int n_in,
                              void* d_out, int out_size, void* d_ws,
                              size_t ws_size, hipStream_t stream) {
  (void)in_sizes; (void)n_in; (void)out_size; (void)ws_size;
  const float* emb  = (const float*)d_in[0];
  const float* W    = (const float*)d_in[1];
  const float* bias = (const float*)d_in[2];
  const float* gnw  = (const float*)d_in[3];
  const float* gnb  = (const float*)d_in[4];
  float* out = (float*)d_out;

  char* ws = (char*)d_ws;
  const size_t perQ = (size_t)BH * L_SEQ * DQ;        // 4,194,304 elems
  unsigned short* embB = (unsigned short*)ws;                      // 8 MB
  unsigned short* WB   = (unsigned short*)(ws + 8u * 1024 * 1024); // 1.5 MB
  unsigned short* Qb   = (unsigned short*)(ws + 10u * 1024 * 1024);
  unsigned short* Kb   = Qb + perQ;   // @18M
  unsigned short* Vb   = Kb + perQ;   // @26M
  float* invz = (float*)(ws + 34u * 1024 * 1024);     // 256 KB
  float* Oacc = (float*)(ws + 35u * 1024 * 1024);     // 16 KB
  int*   cnt  = (int*)(ws + 35u * 1024 * 1024 + 64u * 1024);

  to_bf16<<<dim3(2432), 256, 0, stream>>>(emb, W, embB, WB, Oacc, cnt);
  qkv_mfma<<<dim3(768), 256, 0, stream>>>(embB, WB, bias, Qb, Kb, Vb);
  attn_fused<<<dim3(512), 256, 0, stream>>>(Qb, Kb, Vb, invz, gnw, gnb,
                                            Oacc, cnt, out);
}

// Round 5
// 133.351 us; speedup vs baseline: 1.3965x; 1.3965x over previous
//
#include <hip/hip_runtime.h>
#include <hip/hip_bf16.h>
#include <math.h>

#define L_SEQ 1024
#define BSZ 8
#define EMB 512
#define NH 8
#define DQ 64
#define BH 64          // BSZ*NH
#define NQKV 1536      // 3*NH*DQ

// Q is pre-scaled by (emb_dim/n_head)^-0.5 * log2(e) so that
// softmax numerator = exp2(mfma_score) with zero extra VALU per element.
#define SCALE_Q 0.18033688f

typedef __attribute__((ext_vector_type(8))) short short8;   // 8 bf16 = 4 VGPR
typedef __attribute__((ext_vector_type(4))) float f32x4;

#define GPTR(x) ((const __attribute__((address_space(1))) void*)(x))
#define LPTR(x) ((__attribute__((address_space(3))) void*)(x))

__device__ __forceinline__ unsigned short bf16u(float x) {
  __hip_bfloat16 h = __float2bfloat16(x);
  return *(unsigned short*)&h;
}

// ---------------------------------------------------------------------------
// Kernel 0: f32 -> bf16 convert of emb (8192x512) and W (1536x512).
// (round-2 version, verbatim)
// ---------------------------------------------------------------------------
__global__ __launch_bounds__(256) void to_bf16(
    const float* __restrict__ emb, const float* __restrict__ W,
    unsigned short* __restrict__ embB, unsigned short* __restrict__ WB) {
  const size_t t = (size_t)blockIdx.x * 256 + threadIdx.x;
  size_t base = t * 8;
  const float* src;
  unsigned short* dst;
  size_t off;
  if (base < (size_t)8192 * 512) { src = emb; dst = embB; off = base; }
  else { src = W; dst = WB; off = base - (size_t)8192 * 512; }
  float4 v0 = *(const float4*)&src[off];
  float4 v1 = *(const float4*)&src[off + 4];
  short8 o;
  o[0] = bf16u(v0.x); o[1] = bf16u(v0.y); o[2] = bf16u(v0.z); o[3] = bf16u(v0.w);
  o[4] = bf16u(v1.x); o[5] = bf16u(v1.y); o[6] = bf16u(v1.z); o[7] = bf16u(v1.w);
  *(short8*)&dst[off] = o;
}

// ---------------------------------------------------------------------------
// Kernel A: QKV projection, bf16 MFMA (m97 pattern). Q gets SCALE_Q folded in.
// v8 epilogue (the ONE variable vs round 2): two-pass C staging through
// Cs[128][68] (17 KB instead of 33 KB). LDS total 33 KB -> 4 blocks/CU;
// __launch_bounds__(256,4) caps VGPR at 128 so occupancy reaches 16
// waves/CU. Rationale: the m97 structure's ~20% stall is the vmcnt(0)
// drain before each barrier; more resident blocks hide it (m114 implicit
// wave-level overlap). XCD swizzle (v7) kept: sid = (id&7)*96 + (id>>3).
// ---------------------------------------------------------------------------
__global__ __launch_bounds__(256, 4) void qkv_mfma(
    const unsigned short* __restrict__ A,   // embB [8192][512]
    const unsigned short* __restrict__ B,   // WB   [1536][512]
    const float* __restrict__ bias,
    unsigned short* __restrict__ Qb, unsigned short* __restrict__ Kb,
    unsigned short* __restrict__ Vb) {
  __shared__ __align__(16) unsigned short As[128][32];  // 8 KB, unpadded
  __shared__ __align__(16) unsigned short Bs[128][32];  // 8 KB
  __shared__ __align__(16) unsigned short Cs[128][68];  // 17 KB, +4 pad
  const int tid = threadIdx.x;
  const int wave = tid >> 6, lane = tid & 63;
  const int quad = lane >> 4, col = lane & 15;
  const int wr = wave >> 1, wc = wave & 1;
  // XCD swizzle: 768 blocks, xcd = id&7 (round-robin dispatch), 96 tiles/XCD
  const int id = blockIdx.x;
  const int sid = (id & 7) * 96 + (id >> 3);
  const int mb = sid / 12, nb = sid - mb * 12;
  const int m0 = mb * 128, n0 = nb * 128;
  const int r16 = lane >> 2, q4 = lane & 3;

  f32x4 acc[4][4] = {};

  for (int kt = 0; kt < EMB; kt += 32) {
    __syncthreads();
#pragma unroll
    for (int c = 0; c < 2; ++c) {
      const int rowA = (c * 4 + wave) * 16;
      __builtin_amdgcn_global_load_lds(
          GPTR(A + (size_t)(m0 + rowA + r16) * EMB + kt + q4 * 8),
          LPTR(&As[rowA][0]), 16, 0, 0);
      __builtin_amdgcn_global_load_lds(
          GPTR(B + (size_t)(n0 + rowA + r16) * EMB + kt + q4 * 8),
          LPTR(&Bs[rowA][0]), 16, 0, 0);
    }
    __syncthreads();
    short8 af[4], bf[4];
#pragma unroll
    for (int i = 0; i < 4; ++i)
      af[i] = *(const short8*)&As[wr * 64 + i * 16 + col][quad * 8];
#pragma unroll
    for (int j = 0; j < 4; ++j)
      bf[j] = *(const short8*)&Bs[wc * 64 + j * 16 + col][quad * 8];
#pragma unroll
    for (int i = 0; i < 4; ++i)
#pragma unroll
      for (int j = 0; j < 4; ++j)
        acc[i][j] =
            __builtin_amdgcn_mfma_f32_16x16x32_bf16(af[i], bf[j], acc[i][j],
                                                    0, 0, 0);
  }

  // Two-pass epilogue: half h covers C cols [h*64, h*64+64). The waves with
  // wc==h own those accumulators; all waves then store the staged half.
  const int bb = lane >> 3, oct = lane & 7;
#pragma unroll
  for (int h = 0; h < 2; ++h) {
    __syncthreads();   // h=1: h=0 store-reads of Cs done before overwrite
    if (wc == h) {
#pragma unroll
      for (int j = 0; j < 4; ++j) {
        const int n = j * 16 + col;               // col within half
        const float bj = bias[n0 + h * 64 + n];
        const bool isQ = (((n0 + h * 64 + n) >> 6) % 3) == 0;
#pragma unroll
        for (int i = 0; i < 4; ++i) {
          const int mrow = wr * 64 + i * 16 + quad * 4;
#pragma unroll
          for (int r = 0; r < 4; ++r) {
            float val = acc[i][j][r] + bj;
            if (isQ) val *= SCALE_Q;
            Cs[mrow + r][n] = bf16u(val);
          }
        }
      }
    }
    __syncthreads();
    const int G = (n0 >> 6) + h;          // 64-col block id, 0..23
    const int hd = G / 3, sel = G % 3;
    unsigned short* dst = (sel == 0) ? Qb : (sel == 1) ? Kb : Vb;
#pragma unroll
    for (int e = 0; e < 4; ++e) {
      const int l = wave * 4 + e;         // 0..15
      short8 v = *(const short8*)&Cs[l * 8 + bb][oct * 8];
      const int lglob = (m0 >> 3) + l;
      *(short8*)&dst[(((size_t)(bb * NH + hd)) * L_SEQ + lglob) * DQ + oct * 8] = v;
    }
  }
}

// ---------------------------------------------------------------------------
// Kernel B1: invz[bh][l] = 1 / sum_m exp2(s_lm).
// (round-2 v7 version, verbatim: KVBLK=128, 8 dbuf tiles, post-barrier
// prefetch, 256 threads, 32 q-rows/wave. Also zero-inits Oacc/cnt.)
// ---------------------------------------------------------------------------
__global__ __launch_bounds__(256) void attn_z(
    const unsigned short* __restrict__ Qb, const unsigned short* __restrict__ Kb,
    float* __restrict__ invz, float* __restrict__ Oacc, int* __restrict__ cnt) {
  const int bh = blockIdx.x & 63;   // blk%8 = bh%8 -> same-bh blocks same XCD
  const int qc = blockIdx.x >> 6;   // 0..7, 128 rows each
  const int tid = threadIdx.x;
  const int wave = tid >> 6, lane = tid & 63;
  const int quad = lane >> 4, col = lane & 15;

  __shared__ __align__(16) unsigned short Ks[2][128][72];  // 36.9 KB

  if (qc == 0) {
    if (tid < 64) Oacc[(size_t)bh * 64 + tid] = 0.f;
    if (tid == 0) cnt[bh] = 0;
  }

  const unsigned short* kbase = &Kb[(size_t)bh * L_SEQ * DQ];

  // Q fragments for this wave's 32 rows (2 x 16)
  short8 qa[2][2];
#pragma unroll
  for (int i = 0; i < 2; ++i) {
    const unsigned short* qp =
        &Qb[((size_t)bh * L_SEQ + qc * 128 + wave * 32 + i * 16 + col) * DQ];
    qa[i][0] = *(const short8*)&qp[quad * 8];
    qa[i][1] = *(const short8*)&qp[32 + quad * 8];
  }

  // staging: chunk u covers LDS rows u*32 + (tid>>3), cols (tid&7)*8
  const int srow = tid >> 3;        // 0..31
  const int scol = (tid & 7) * 8;   // shorts

  float zacc[2][4] = {};

  short8 st0, st1, st2, st3;
  {  // prefetch tile 0 (tile kt = 16 KB contiguous at kbase + kt*8192)
    st0 = *(const short8*)(kbase + (size_t)tid * 8);
    st1 = *(const short8*)(kbase + 2048 + (size_t)tid * 8);
    st2 = *(const short8*)(kbase + 4096 + (size_t)tid * 8);
    st3 = *(const short8*)(kbase + 6144 + (size_t)tid * 8);
  }

#pragma unroll 2
  for (int kt = 0; kt < 8; ++kt) {
    const int buf = kt & 1;
    *(short8*)&Ks[buf][srow][scol] = st0;
    *(short8*)&Ks[buf][32 + srow][scol] = st1;
    *(short8*)&Ks[buf][64 + srow][scol] = st2;
    *(short8*)&Ks[buf][96 + srow][scol] = st3;
    __syncthreads();
    if (kt + 1 < 8) {  // post-barrier prefetch: in flight through compute
      const unsigned short* nb = kbase + (size_t)(kt + 1) * 8192;
      st0 = *(const short8*)(nb + (size_t)tid * 8);
      st1 = *(const short8*)(nb + 2048 + (size_t)tid * 8);
      st2 = *(const short8*)(nb + 4096 + (size_t)tid * 8);
      st3 = *(const short8*)(nb + 6144 + (size_t)tid * 8);
    }
#pragma unroll
    for (int sub = 0; sub < 8; ++sub) {
      const unsigned short* kp = &Ks[buf][sub * 16 + col][0];
      short8 kb0 = *(const short8*)&kp[quad * 8];
      short8 kb1 = *(const short8*)&kp[32 + quad * 8];
#pragma unroll
      for (int i = 0; i < 2; ++i) {
        f32x4 s = {0.f, 0.f, 0.f, 0.f};
        s = __builtin_amdgcn_mfma_f32_16x16x32_bf16(qa[i][0], kb0, s, 0, 0, 0);
        s = __builtin_amdgcn_mfma_f32_16x16x32_bf16(qa[i][1], kb1, s, 0, 0, 0);
#pragma unroll
        for (int j = 0; j < 4; ++j) zacc[i][j] += __builtin_amdgcn_exp2f(s[j]);
      }
    }
  }
  float* dst = &invz[(size_t)bh * L_SEQ + qc * 128 + wave * 32];
#pragma unroll
  for (int i = 0; i < 2; ++i)
#pragma unroll
    for (int j = 0; j < 4; ++j) {
      float z = zacc[i][j];
#pragma unroll
      for (int off = 1; off <= 8; off <<= 1) z += __shfl_xor(z, off, 64);
      if (col == j)
        dst[i * 16 + quad * 4 + j] = __builtin_amdgcn_rcpf(z);
    }
}

// ---------------------------------------------------------------------------
// Kernel B2 (round-2 v7 version, verbatim): 256-thread blocks, 4 waves,
// 32 keys/wave, Q-tile 128 rows, 8 dbuf iterations. After the sweep: aw
// -> LDS, local V-combine, atomicAdd Oacc; 8th block per bh does
// GroupNorm + out (G16-safe: device-scope atomics + threadfence).
// ---------------------------------------------------------------------------
__global__ __launch_bounds__(256) void attn_aw(
    const unsigned short* __restrict__ Qb, const unsigned short* __restrict__ Kb,
    const unsigned short* __restrict__ Vb, const float* __restrict__ invz,
    const float* __restrict__ gnw, const float* __restrict__ gnb,
    float* __restrict__ Oacc, int* __restrict__ cnt, float* __restrict__ out) {
  const int bh = blockIdx.x & 63;
  const int kc = blockIdx.x >> 6;   // 0..7, 128 keys each
  const int tid = threadIdx.x;
  const int wave = tid >> 6, lane = tid & 63;
  const int quad = lane >> 4, col = lane & 15;

  __shared__ __align__(16) unsigned short Qs[2][128][72];  // 36.9 KB
  __shared__ float izs[1024];                              // 4 KB
  __shared__ float aws[128];
  __shared__ float red[4][64];
  __shared__ int lastFlag;

  const unsigned short* qbase = &Qb[(size_t)bh * L_SEQ * DQ];

  // K fragments for this wave's 32 keys (2 x 16)
  short8 kA[2][2];
#pragma unroll
  for (int i = 0; i < 2; ++i) {
    const unsigned short* kp0 =
        &Kb[((size_t)bh * L_SEQ + kc * 128 + wave * 32 + i * 16 + col) * DQ];
    kA[i][0] = *(const short8*)&kp0[quad * 8];
    kA[i][1] = *(const short8*)&kp0[32 + quad * 8];
  }

  {  // stage invz for this bh (visible after first in-loop barrier)
    const float4 v = *(const float4*)&invz[(size_t)bh * L_SEQ + tid * 4];
    *(float4*)&izs[tid * 4] = v;
  }

  const int srow = tid >> 3;
  const int scol = (tid & 7) * 8;

  float acc[2][4] = {};

  short8 st0, st1, st2, st3;
  {  // prefetch tile 0 (Q tiles are 16 KB contiguous)
    st0 = *(const short8*)(qbase + (size_t)tid * 8);
    st1 = *(const short8*)(qbase + 2048 + (size_t)tid * 8);
    st2 = *(const short8*)(qbase + 4096 + (size_t)tid * 8);
    st3 = *(const short8*)(qbase + 6144 + (size_t)tid * 8);
  }

#pragma unroll 2
  for (int qt = 0; qt < 8; ++qt) {
    const int buf = qt & 1;
    *(short8*)&Qs[buf][srow][scol] = st0;
    *(short8*)&Qs[buf][32 + srow][scol] = st1;
    *(short8*)&Qs[buf][64 + srow][scol] = st2;
    *(short8*)&Qs[buf][96 + srow][scol] = st3;
    __syncthreads();
    if (qt + 1 < 8) {  // post-barrier prefetch
      const unsigned short* nb = qbase + (size_t)(qt + 1) * 8192;
      st0 = *(const short8*)(nb + (size_t)tid * 8);
      st1 = *(const short8*)(nb + 2048 + (size_t)tid * 8);
      st2 = *(const short8*)(nb + 4096 + (size_t)tid * 8);
      st3 = *(const short8*)(nb + 6144 + (size_t)tid * 8);
    }
#pragma unroll
    for (int sub = 0; sub < 8; ++sub) {
      const unsigned short* qp = &Qs[buf][sub * 16 + col][0];
      short8 qb0 = *(const short8*)&qp[quad * 8];
      short8 qb1 = *(const short8*)&qp[32 + quad * 8];
      const float ivzv = izs[qt * 128 + sub * 16 + col];
#pragma unroll
      for (int i = 0; i < 2; ++i) {
        f32x4 s = {0.f, 0.f, 0.f, 0.f};
        s = __builtin_amdgcn_mfma_f32_16x16x32_bf16(kA[i][0], qb0, s, 0, 0, 0);
        s = __builtin_amdgcn_mfma_f32_16x16x32_bf16(kA[i][1], qb1, s, 0, 0, 0);
#pragma unroll
        for (int r = 0; r < 4; ++r)
          acc[i][r] = fmaf(__builtin_amdgcn_exp2f(s[r]), ivzv, acc[i][r]);
      }
    }
  }
  // butterfly over the 16 query-lanes; lane col==r holds key quad*4+r
#pragma unroll
  for (int i = 0; i < 2; ++i)
#pragma unroll
    for (int r = 0; r < 4; ++r) {
      float a = acc[i][r];
#pragma unroll
      for (int off = 1; off <= 8; off <<= 1) a += __shfl_xor(a, off, 64);
      if (col == r) aws[wave * 32 + i * 16 + quad * 4 + r] = a;
    }
  __syncthreads();

  // local V-combine over this block's 128 keys (4 groups x 32 keys)
  const int d = tid & 63, g4 = tid >> 6;
  float oacc = 0.f;
#pragma unroll 8
  for (int mm = 0; mm < 32; ++mm) {
    const int m = g4 * 32 + mm;
    __hip_bfloat16 v;
    *(unsigned short*)&v =
        Vb[((size_t)bh * L_SEQ + kc * 128 + m) * DQ + d];
    oacc = fmaf(aws[m], __bfloat162float(v), oacc);
  }
  red[g4][d] = oacc;
  __syncthreads();
  if (tid < 64) {
    float p = red[0][tid] + red[1][tid] + red[2][tid] + red[3][tid];
    atomicAdd(&Oacc[(size_t)bh * 64 + tid], p);
  }
  if (tid == 0) {
    __threadfence();                      // release: O adds visible first
    lastFlag = (atomicAdd(&cnt[bh], 1) == 7);
  }
  __syncthreads();
  if (lastFlag && tid < 64) {
    __threadfence();                      // acquire
    float v = atomicAdd(&Oacc[(size_t)bh * 64 + tid], 0.f);
    float s = v;
#pragma unroll
    for (int off = 32; off >= 1; off >>= 1) s += __shfl_xor(s, off, 64);
    float mean = s * (1.f / 64.f);
    float diff = v - mean;
    float sq = diff * diff;
#pragma unroll
    for (int off = 32; off >= 1; off >>= 1) sq += __shfl_xor(sq, off, 64);
    float var = sq * (1.f / 64.f);
    float o = diff * rsqrtf(var + 1e-5f);
    const int b = bh >> 3, h = bh & 7;
    out[(size_t)b * 512 + h * 64 + tid] = o * gnw[h] + gnb[h];
  }
}

extern "C" void kernel_launch(void* const* d_in, const int* in_sizes, int n_in,
                              void* d_out, int out_size, void* d_ws,
                              size_t ws_size, hipStream_t stream) {
  (void)in_sizes; (void)n_in; (void)out_size; (void)ws_size;
  const float* emb  = (const float*)d_in[0];
  const float* W    = (const float*)d_in[1];
  const float* bias = (const float*)d_in[2];
  const float* gnw  = (const float*)d_in[3];
  const float* gnb  = (const float*)d_in[4];
  float* out = (float*)d_out;

  char* ws = (char*)d_ws;
  const size_t perQ = (size_t)BH * L_SEQ * DQ;        // 4,194,304 elems
  unsigned short* embB = (unsigned short*)ws;                      // 8 MB
  unsigned short* WB   = (unsigned short*)(ws + 8u * 1024 * 1024); // 1.5 MB
  unsigned short* Qb   = (unsigned short*)(ws + 10u * 1024 * 1024);
  unsigned short* Kb   = Qb + perQ;   // @18M
  unsigned short* Vb   = Kb + perQ;   // @26M
  float* invz = (float*)(ws + 34u * 1024 * 1024);     // 256 KB
  float* Oacc = (float*)(ws + 35u * 1024 * 1024);     // 16 KB
  int*   cnt  = (int*)(ws + 35u * 1024 * 1024 + 64u * 1024);

  to_bf16<<<dim3(2432), 256, 0, stream>>>(emb, W, embB, WB);
  qkv_mfma<<<dim3(768), 256, 0, stream>>>(embB, WB, bias, Qb, Kb, Vb);
  attn_z<<<dim3(512), 256, 0, stream>>>(Qb, Kb, invz, Oacc, cnt);
  attn_aw<<<dim3(512), 256, 0, stream>>>(Qb, Kb, Vb, invz, gnw, gnb,
                                         Oacc, cnt, out);
}